// Round 4
// baseline (3553.498 us; speedup 1.0000x reference)
//
#include <hip/hip_runtime.h>
#include <cstddef>

#define BATCH   8
#define LSEQ    4096
#define DMODEL  128
#define DINNER  256
#define NSTATE  16
#define NLAYER  4
#define MROWS   (BATCH*LSEQ)   // 32768

__device__ __forceinline__ float silu_f(float v) { return v / (1.f + expf(-v)); }
__device__ __forceinline__ float softplus_f(float v) {
  return v > 20.f ? v : log1pf(expf(v));
}

// ---------------------------------------------------------------------------
// Generic tiled GEMM: C = A[M,K] @ W[N,K]^T
// mode 0: out0[m*N + n] = c
// mode 1: (N==512) n<256 -> out0[m*256+n] = c (raw xa); n>=256 -> out1 = silu(c)
// ---------------------------------------------------------------------------
__global__ __launch_bounds__(256) void gemm_awt(
    const float* __restrict__ A, const float* __restrict__ W,
    float* __restrict__ out0, float* __restrict__ out1,
    int M, int N, int K, int mode)
{
  __shared__ float As[32][68];
  __shared__ float Bs[32][68];
  const int m0 = blockIdx.x * 64;
  const int n0 = blockIdx.y * 64;
  const int t  = threadIdx.x;
  const int tx = t & 15, ty = t >> 4;
  const int kk_s = t & 31, row_s = t >> 5;

  float acc[4][4] = {};

  for (int k0 = 0; k0 < K; k0 += 32) {
#pragma unroll
    for (int p = 0; p < 8; ++p) {
      int r = row_s + p * 8;
      As[kk_s][r] = A[(size_t)(m0 + r) * K + (k0 + kk_s)];
      Bs[kk_s][r] = W[(size_t)(n0 + r) * K + (k0 + kk_s)];
    }
    __syncthreads();
#pragma unroll
    for (int kk = 0; kk < 32; ++kk) {
      float4 a4 = *(const float4*)&As[kk][ty * 4];
      float4 b4 = *(const float4*)&Bs[kk][tx * 4];
      float av[4] = {a4.x, a4.y, a4.z, a4.w};
      float bv[4] = {b4.x, b4.y, b4.z, b4.w};
#pragma unroll
      for (int i = 0; i < 4; ++i)
#pragma unroll
        for (int j = 0; j < 4; ++j)
          acc[i][j] = fmaf(av[i], bv[j], acc[i][j]);
    }
    __syncthreads();
  }

#pragma unroll
  for (int i = 0; i < 4; ++i) {
    int m = m0 + ty * 4 + i;
    float4 c4 = make_float4(acc[i][0], acc[i][1], acc[i][2], acc[i][3]);
    if (mode == 0) {
      *(float4*)&out0[(size_t)m * N + n0 + tx * 4] = c4;
    } else {
      int n = n0 + tx * 4;
      if (n < 256) {
        *(float4*)&out0[(size_t)m * 256 + n] = c4;
      } else {
        c4.x = silu_f(c4.x); c4.y = silu_f(c4.y);
        c4.z = silu_f(c4.z); c4.w = silu_f(c4.w);
        *(float4*)&out1[(size_t)m * 256 + (n - 256)] = c4;
      }
    }
  }
}

// ---------------------------------------------------------------------------
// Causal depthwise conv (k=4) + bias + silu, with [M,256] -> [B,256,L] transpose
// ---------------------------------------------------------------------------
__global__ __launch_bounds__(256) void conv_silu_t(
    const float* __restrict__ xa_rm,   // [M,256]
    const float* __restrict__ cw,      // [256,4]
    const float* __restrict__ cb,      // [256]
    float* __restrict__ xa_t)          // [B,256,L]
{
  __shared__ float tile[64][133];      // [dd][li], li=0 ~ l0-3
  __shared__ float s_cw[64][4];
  __shared__ float s_cb[64];
  const int b  = blockIdx.z;
  const int d0 = blockIdx.y * 64;
  const int l0 = blockIdx.x * 128;
  const int t  = threadIdx.x;

  if (t < 64) {
    s_cb[t] = cb[d0 + t];
#pragma unroll
    for (int k = 0; k < 4; ++k) s_cw[t][k] = cw[(d0 + t) * 4 + k];
  }
  const int dd_st = t & 63;
  for (int li = t >> 6; li < 131; li += 4) {
    int l = l0 - 3 + li;
    float v = 0.f;
    if (l >= 0) v = xa_rm[((size_t)(b * LSEQ + l)) * 256 + d0 + dd_st];
    tile[dd_st][li] = v;
  }
  __syncthreads();

  for (int idx = t; idx < 64 * 128; idx += 256) {
    int dd = idx >> 7;
    int lc = idx & 127;
    float v = s_cb[dd]
            + tile[dd][lc + 0] * s_cw[dd][0]
            + tile[dd][lc + 1] * s_cw[dd][1]
            + tile[dd][lc + 2] * s_cw[dd][2]
            + tile[dd][lc + 3] * s_cw[dd][3];
    v = silu_f(v);
    xa_t[((size_t)(b * DINNER + d0 + dd)) * LSEQ + l0 + lc] = v;
  }
}

// ---------------------------------------------------------------------------
// Fused x_proj (40x256) + dt_proj (256x8) + softplus.
// Writes dt_t [B,256,L], Bt/Ct [B,16,L]  (state-major, L-contiguous).
// ---------------------------------------------------------------------------
__global__ __launch_bounds__(256) void proj_dt(
    const float* __restrict__ xa_t,    // [B,256,L]
    const float* __restrict__ xp_w,    // [40,256]
    const float* __restrict__ dtp_w,   // [256,8]
    const float* __restrict__ dtp_b,   // [256]
    float* __restrict__ dt_t,          // [B,256,L]
    float* __restrict__ Bt,            // [B,16,L]
    float* __restrict__ Ct)            // [B,16,L]
{
  __shared__ float s_xpc[40][68];
  __shared__ float s_dtw[256 * 8];
  __shared__ float s_dtb[256];
  __shared__ float s_xa[64][68];
  __shared__ float s_proj[64][44];
  const int b  = blockIdx.y;
  const int l0 = blockIdx.x * 64;
  const int t  = threadIdx.x;

  for (int i = t; i < 256 * 8; i += 256) s_dtw[i] = dtp_w[i];
  s_dtb[t] = dtp_b[t];

  const int ll_st  = t & 63;
  const int kk0_st = t >> 6;
  const int kk_w   = t & 63;
  const int nb_w   = t >> 6;
  const int lA = t & 31;
  const int g  = t >> 5;

  float acc0[5] = {}, acc1[5] = {};

  for (int kc = 0; kc < 256; kc += 64) {
    __syncthreads();
#pragma unroll
    for (int p = 0; p < 16; ++p) {
      int kk = kk0_st + p * 4;
      s_xa[ll_st][kk] =
          xa_t[((size_t)(b * DINNER + kc + kk)) * LSEQ + l0 + ll_st];
    }
#pragma unroll
    for (int p = 0; p < 10; ++p) {
      int n = nb_w + p * 4;
      s_xpc[n][kk_w] = xp_w[n * 256 + kc + kk_w];
    }
    __syncthreads();
#pragma unroll
    for (int kk = 0; kk < 64; kk += 4) {
      float4 a0 = *(const float4*)&s_xa[lA][kk];
      float4 a1 = *(const float4*)&s_xa[lA + 32][kk];
#pragma unroll
      for (int j = 0; j < 5; ++j) {
        float4 w4 = *(const float4*)&s_xpc[g * 5 + j][kk];
        acc0[j] = fmaf(a0.x, w4.x, fmaf(a0.y, w4.y,
                  fmaf(a0.z, w4.z, fmaf(a0.w, w4.w, acc0[j]))));
        acc1[j] = fmaf(a1.x, w4.x, fmaf(a1.y, w4.y,
                  fmaf(a1.z, w4.z, fmaf(a1.w, w4.w, acc1[j]))));
      }
    }
  }
  __syncthreads();
#pragma unroll
  for (int j = 0; j < 5; ++j) {
    s_proj[lA][g * 5 + j]      = acc0[j];
    s_proj[lA + 32][g * 5 + j] = acc1[j];
  }
  __syncthreads();

  const int ll = t & 63;
  const int dgroup = t >> 6;
  float4 p0 = *(const float4*)&s_proj[ll][0];
  float4 p1 = *(const float4*)&s_proj[ll][4];
  for (int j = 0; j < 64; ++j) {
    int dout = dgroup * 64 + j;
    float4 w0 = *(const float4*)&s_dtw[dout * 8];
    float4 w1 = *(const float4*)&s_dtw[dout * 8 + 4];
    float v = s_dtb[dout]
            + p0.x * w0.x + p0.y * w0.y + p0.z * w0.z + p0.w * w0.w
            + p1.x * w1.x + p1.y * w1.y + p1.z * w1.z + p1.w * w1.w;
    dt_t[((size_t)(b * DINNER + dout)) * LSEQ + l0 + ll] = softplus_f(v);
  }
  // Bt/Ct: [B,16,L] — 64 consecutive l-addresses per instruction (coalesced)
  if (t < 64) {
#pragma unroll
    for (int nn = 0; nn < 16; ++nn)
      Bt[((size_t)(b * NSTATE + nn)) * LSEQ + l0 + t] = s_proj[t][8 + nn];
  } else if (t < 128) {
    int lw = t - 64;
#pragma unroll
    for (int nn = 0; nn < 16; ++nn)
      Ct[((size_t)(b * NSTATE + nn)) * LSEQ + l0 + lw] = s_proj[lw][24 + nn];
  }
}

// ---------------------------------------------------------------------------
// Selective scan — EXACT sequential recurrence (same op order as the R0/R3
// kernels, absmax 1.455e-11). Per-step cross-lane shfl butterfly replaced by
// LDS-deferred batched reduction every 16 steps, with a binary sum tree that
// is bitwise-identical to the shfl_xor(1,2,4,8) butterfly at lane n=0.
// Fuses fmaf(u,D,·), *silu(z) and the [M,256] row-major store (transmul gone).
// 16 lanes (one per state n) per (b,d) channel; 4 channels/wave.
// grid: BATCH * DINNER/4 = 512 blocks of 64 threads.
// ---------------------------------------------------------------------------
__global__ __launch_bounds__(64) void scan_k(
    const float* __restrict__ dt_t, const float* __restrict__ u_t,
    const float* __restrict__ Bt,   const float* __restrict__ Ct,
    const float* __restrict__ A_log, const float* __restrict__ Dp,
    const float* __restrict__ zs,    // [M,256] = silu(z)
    float* __restrict__ ymul)        // [M,256] = y * silu(z)
{
  // row r (= reduction lane id) holds 16 partials (words 0..15) + u (word 16)
  __shared__ float lp[2][64 * 20];
  const int blk = blockIdx.x;
  const int b   = blk >> 6;
  const int d0  = (blk & 63) * 4;
  const int lane = threadIdx.x;
  const int g = lane >> 4;         // channel within wave (writer phase)
  const int n = lane & 15;         // state (writer phase)
  const int d = d0 + g;
  const int rs = lane >> 2;        // step-in-group   (reduction phase)
  const int rg = lane & 3;         // channel         (reduction phase)

  const float Aa  = -expf(A_log[d * NSTATE + n]);
  const float Dvr = Dp[d0 + rg];
  const float4* dtp = (const float4*)(dt_t + ((size_t)(b * DINNER + d)) * LSEQ);
  const float4* up  = (const float4*)(u_t  + ((size_t)(b * DINNER + d)) * LSEQ);
  const float4* Bp  = (const float4*)(Bt + ((size_t)(b * NSTATE + n)) * LSEQ);
  const float4* Cp  = (const float4*)(Ct + ((size_t)(b * NSTATE + n)) * LSEQ);

  const int NG = LSEQ / 16;        // 256 groups of 16 steps
  float4 Rd[2][4], Ru[2][4], Rb[2][4], Rc[2][4];
  float zpre[2];
  float h = 0.f;

#define LOAD_GRP(s, grp) do {                                            \
    int _base = (grp) * 4;                                               \
    _Pragma("unroll")                                                    \
    for (int q = 0; q < 4; ++q) {                                        \
      Rd[s][q] = dtp[_base + q];  Ru[s][q] = up[_base + q];              \
      Rb[s][q] = Bp[_base + q];   Rc[s][q] = Cp[_base + q];              \
    }                                                                    \
    zpre[s] = zs[((size_t)b * LSEQ + (grp) * 16 + rs) * 256 + d0 + rg];  \
  } while (0)

  LOAD_GRP(0, 0);
  for (int it = 0; it < NG; ++it) {
    const int cb = it & 1;
    if (it + 1 < NG) LOAD_GRP(cb ^ 1, it + 1);

    // ---- writer phase: h-chain + LDS partials (no cross-lane deps) ----
    float* Lw = lp[cb];
#pragma unroll
    for (int q = 0; q < 4; ++q) {
      float dts[4] = {Rd[cb][q].x, Rd[cb][q].y, Rd[cb][q].z, Rd[cb][q].w};
      float us[4]  = {Ru[cb][q].x, Ru[cb][q].y, Ru[cb][q].z, Ru[cb][q].w};
      float bv[4]  = {Rb[cb][q].x, Rb[cb][q].y, Rb[cb][q].z, Rb[cb][q].w};
      float cv[4]  = {Rc[cb][q].x, Rc[cb][q].y, Rc[cb][q].z, Rc[cb][q].w};
#pragma unroll
      for (int st = 0; st < 4; ++st) {
        float a = expf(dts[st] * Aa);
        h = fmaf(a, h, (dts[st] * us[st]) * bv[st]);
        int row = (q * 4 + st) * 4 + g;
        Lw[row * 20 + n] = h * cv[st];
        if (n == 0) Lw[row * 20 + 16] = us[st];
      }
    }
    __syncthreads();

    // ---- reduction phase: lane = row = (rs,rg) ----
    const float* r = lp[cb] + lane * 20;
    float4 pA = *(const float4*)(r + 0);
    float4 pB = *(const float4*)(r + 4);
    float4 pC = *(const float4*)(r + 8);
    float4 pD = *(const float4*)(r + 12);
    float usv = r[16];
    // bitwise-identical to shfl_xor(1),(2),(4),(8) at lane n==0
    float s01 = pA.x + pA.y, s23 = pA.z + pA.w;
    float s45 = pB.x + pB.y, s67 = pB.z + pB.w;
    float s89 = pC.x + pC.y, sab = pC.z + pC.w;
    float scd = pD.x + pD.y, sef = pD.z + pD.w;
    float q0 = s01 + s23, q1 = s45 + s67;
    float q2 = s89 + sab, q3 = scd + sef;
    float o0 = q0 + q1, o1 = q2 + q3;
    float ysum = o0 + o1;
    float ys = fmaf(usv, Dvr, ysum);
    size_t addr = ((size_t)b * LSEQ + it * 16 + rs) * 256 + d0 + rg;
    ymul[addr] = ys * zpre[cb];
  }
#undef LOAD_GRP
}

// ---------------------------------------------------------------------------
extern "C" void kernel_launch(void* const* d_in, const int* in_sizes, int n_in,
                              void* d_out, int out_size, void* d_ws, size_t ws_size,
                              hipStream_t stream) {
  const float* x_in  = (const float*)d_in[0];
  const float* w_in  = (const float*)d_in[1];   // [4,512,128]
  const float* cw    = (const float*)d_in[2];   // [4,256,4]
  const float* cb    = (const float*)d_in[3];   // [4,256]
  const float* xpw   = (const float*)d_in[4];   // [4,40,256]
  const float* dtw   = (const float*)d_in[5];   // [4,256,8]
  const float* dtb   = (const float*)d_in[6];   // [4,256]
  const float* alog  = (const float*)d_in[7];   // [4,256,16]
  const float* Dp    = (const float*)d_in[8];   // [4,256]
  const float* ow    = (const float*)d_in[9];   // [4,128,256]
  float* out = (float*)d_out;

  const size_t M = MROWS;
  float* f0 = (float*)d_ws;            // x ping  [M,128]
  float* f1 = f0 + M * 128;            // x pong  [M,128]
  float* f2 = f1 + M * 128;            // xa_pre -> dt_t [B,256,L]
  float* f3 = f2 + M * 256;            // zs = silu(z) [M,256]
  float* f4 = f3 + M * 256;            // xa_t [B,256,L]
  float* f6 = f4 + M * 256;            // Bt [B,16,L]
  float* f7 = f6 + M * 16;             // Ct [B,16,L]
  float* f8 = f7 + M * 16;             // ymul [M,256]

  const float* cur = x_in;
  for (int i = 0; i < NLAYER; ++i) {
    float* xout = (i == NLAYER - 1) ? out : ((i % 2 == 0) ? f0 : f1);
    const float* wi  = w_in + (size_t)i * 512 * 128;
    const float* cwi = cw   + (size_t)i * 256 * 4;
    const float* cbi = cb   + (size_t)i * 256;
    const float* xpi = xpw  + (size_t)i * 40 * 256;
    const float* dwi = dtw  + (size_t)i * 256 * 8;
    const float* dbi = dtb  + (size_t)i * 256;
    const float* ali = alog + (size_t)i * 256 * 16;
    const float* dpi = Dp   + (size_t)i * 256;
    const float* owi = ow   + (size_t)i * 128 * 256;

    // 1. in_proj: [M,128]@[512,128]^T -> xa_pre(f2), silu(z)(f3)
    gemm_awt<<<dim3(MROWS / 64, 8), 256, 0, stream>>>(
        cur, wi, f2, f3, MROWS, 512, 128, 1);
    // 2. conv + silu + transpose -> xa_t (f4)
    conv_silu_t<<<dim3(LSEQ / 128, DINNER / 64, BATCH), 256, 0, stream>>>(
        f2, cwi, cbi, f4);
    // 3. x_proj + dt_proj + softplus -> dt_t(f2), Bt(f6), Ct(f7)
    proj_dt<<<dim3(LSEQ / 64, BATCH), 256, 0, stream>>>(
        f4, xpi, dwi, dbi, f2, f6, f7);
    // 4. selective scan (exact sequential) + *silu(z) fused -> ymul (f8)
    scan_k<<<dim3(BATCH * DINNER / 4), 64, 0, stream>>>(
        f2, f4, f6, f7, ali, dpi, f3, f8);
    // 5. out_proj: [M,256]@[128,256]^T -> xout
    gemm_awt<<<dim3(MROWS / 64, 2), 256, 0, stream>>>(
        f8, owi, xout, nullptr, MROWS, 128, 256, 0);

    cur = xout;
  }
}

// Round 5
// 2304.653 us; speedup vs baseline: 1.5419x; 1.5419x over previous
//
#include <hip/hip_runtime.h>
#include <cstddef>

#define BATCH   8
#define LSEQ    4096
#define DMODEL  128
#define DINNER  256
#define NSTATE  16
#define NLAYER  4
#define MROWS   (BATCH*LSEQ)   // 32768

__device__ __forceinline__ float silu_f(float v) { return v / (1.f + expf(-v)); }
__device__ __forceinline__ float softplus_f(float v) {
  return v > 20.f ? v : log1pf(expf(v));
}

// ---------------------------------------------------------------------------
// Generic tiled GEMM: C = A[M,K] @ W[N,K]^T
// mode 0: out0[m*N + n] = c
// mode 1: (N==512) n<256 -> out0[m*256+n] = c (raw xa); n>=256 -> out1 = silu(c)
// ---------------------------------------------------------------------------
__global__ __launch_bounds__(256) void gemm_awt(
    const float* __restrict__ A, const float* __restrict__ W,
    float* __restrict__ out0, float* __restrict__ out1,
    int M, int N, int K, int mode)
{
  __shared__ float As[32][68];
  __shared__ float Bs[32][68];
  const int m0 = blockIdx.x * 64;
  const int n0 = blockIdx.y * 64;
  const int t  = threadIdx.x;
  const int tx = t & 15, ty = t >> 4;
  const int kk_s = t & 31, row_s = t >> 5;

  float acc[4][4] = {};

  for (int k0 = 0; k0 < K; k0 += 32) {
#pragma unroll
    for (int p = 0; p < 8; ++p) {
      int r = row_s + p * 8;
      As[kk_s][r] = A[(size_t)(m0 + r) * K + (k0 + kk_s)];
      Bs[kk_s][r] = W[(size_t)(n0 + r) * K + (k0 + kk_s)];
    }
    __syncthreads();
#pragma unroll
    for (int kk = 0; kk < 32; ++kk) {
      float4 a4 = *(const float4*)&As[kk][ty * 4];
      float4 b4 = *(const float4*)&Bs[kk][tx * 4];
      float av[4] = {a4.x, a4.y, a4.z, a4.w};
      float bv[4] = {b4.x, b4.y, b4.z, b4.w};
#pragma unroll
      for (int i = 0; i < 4; ++i)
#pragma unroll
        for (int j = 0; j < 4; ++j)
          acc[i][j] = fmaf(av[i], bv[j], acc[i][j]);
    }
    __syncthreads();
  }

#pragma unroll
  for (int i = 0; i < 4; ++i) {
    int m = m0 + ty * 4 + i;
    float4 c4 = make_float4(acc[i][0], acc[i][1], acc[i][2], acc[i][3]);
    if (mode == 0) {
      *(float4*)&out0[(size_t)m * N + n0 + tx * 4] = c4;
    } else {
      int n = n0 + tx * 4;
      if (n < 256) {
        *(float4*)&out0[(size_t)m * 256 + n] = c4;
      } else {
        c4.x = silu_f(c4.x); c4.y = silu_f(c4.y);
        c4.z = silu_f(c4.z); c4.w = silu_f(c4.w);
        *(float4*)&out1[(size_t)m * 256 + (n - 256)] = c4;
      }
    }
  }
}

// ---------------------------------------------------------------------------
// Causal depthwise conv (k=4) + bias + silu, with [M,256] -> [B,256,L] transpose
// ---------------------------------------------------------------------------
__global__ __launch_bounds__(256) void conv_silu_t(
    const float* __restrict__ xa_rm,   // [M,256]
    const float* __restrict__ cw,      // [256,4]
    const float* __restrict__ cb,      // [256]
    float* __restrict__ xa_t)          // [B,256,L]
{
  __shared__ float tile[64][133];      // [dd][li], li=0 ~ l0-3
  __shared__ float s_cw[64][4];
  __shared__ float s_cb[64];
  const int b  = blockIdx.z;
  const int d0 = blockIdx.y * 64;
  const int l0 = blockIdx.x * 128;
  const int t  = threadIdx.x;

  if (t < 64) {
    s_cb[t] = cb[d0 + t];
#pragma unroll
    for (int k = 0; k < 4; ++k) s_cw[t][k] = cw[(d0 + t) * 4 + k];
  }
  const int dd_st = t & 63;
  for (int li = t >> 6; li < 131; li += 4) {
    int l = l0 - 3 + li;
    float v = 0.f;
    if (l >= 0) v = xa_rm[((size_t)(b * LSEQ + l)) * 256 + d0 + dd_st];
    tile[dd_st][li] = v;
  }
  __syncthreads();

  for (int idx = t; idx < 64 * 128; idx += 256) {
    int dd = idx >> 7;
    int lc = idx & 127;
    float v = s_cb[dd]
            + tile[dd][lc + 0] * s_cw[dd][0]
            + tile[dd][lc + 1] * s_cw[dd][1]
            + tile[dd][lc + 2] * s_cw[dd][2]
            + tile[dd][lc + 3] * s_cw[dd][3];
    v = silu_f(v);
    xa_t[((size_t)(b * DINNER + d0 + dd)) * LSEQ + l0 + lc] = v;
  }
}

// ---------------------------------------------------------------------------
// Fused x_proj (40x256) + dt_proj (256x8) + softplus.
// Writes dt_t [B,256,L], Bt/Ct [B,16,L]  (state-major, L-contiguous).
// ---------------------------------------------------------------------------
__global__ __launch_bounds__(256) void proj_dt(
    const float* __restrict__ xa_t,    // [B,256,L]
    const float* __restrict__ xp_w,    // [40,256]
    const float* __restrict__ dtp_w,   // [256,8]
    const float* __restrict__ dtp_b,   // [256]
    float* __restrict__ dt_t,          // [B,256,L]
    float* __restrict__ Bt,            // [B,16,L]
    float* __restrict__ Ct)            // [B,16,L]
{
  __shared__ float s_xpc[40][68];
  __shared__ float s_dtw[256 * 8];
  __shared__ float s_dtb[256];
  __shared__ float s_xa[64][68];
  __shared__ float s_proj[64][44];
  const int b  = blockIdx.y;
  const int l0 = blockIdx.x * 64;
  const int t  = threadIdx.x;

  for (int i = t; i < 256 * 8; i += 256) s_dtw[i] = dtp_w[i];
  s_dtb[t] = dtp_b[t];

  const int ll_st  = t & 63;
  const int kk0_st = t >> 6;
  const int kk_w   = t & 63;
  const int nb_w   = t >> 6;
  const int lA = t & 31;
  const int g  = t >> 5;

  float acc0[5] = {}, acc1[5] = {};

  for (int kc = 0; kc < 256; kc += 64) {
    __syncthreads();
#pragma unroll
    for (int p = 0; p < 16; ++p) {
      int kk = kk0_st + p * 4;
      s_xa[ll_st][kk] =
          xa_t[((size_t)(b * DINNER + kc + kk)) * LSEQ + l0 + ll_st];
    }
#pragma unroll
    for (int p = 0; p < 10; ++p) {
      int n = nb_w + p * 4;
      s_xpc[n][kk_w] = xp_w[n * 256 + kc + kk_w];
    }
    __syncthreads();
#pragma unroll
    for (int kk = 0; kk < 64; kk += 4) {
      float4 a0 = *(const float4*)&s_xa[lA][kk];
      float4 a1 = *(const float4*)&s_xa[lA + 32][kk];
#pragma unroll
      for (int j = 0; j < 5; ++j) {
        float4 w4 = *(const float4*)&s_xpc[g * 5 + j][kk];
        acc0[j] = fmaf(a0.x, w4.x, fmaf(a0.y, w4.y,
                  fmaf(a0.z, w4.z, fmaf(a0.w, w4.w, acc0[j]))));
        acc1[j] = fmaf(a1.x, w4.x, fmaf(a1.y, w4.y,
                  fmaf(a1.z, w4.z, fmaf(a1.w, w4.w, acc1[j]))));
      }
    }
  }
  __syncthreads();
#pragma unroll
  for (int j = 0; j < 5; ++j) {
    s_proj[lA][g * 5 + j]      = acc0[j];
    s_proj[lA + 32][g * 5 + j] = acc1[j];
  }
  __syncthreads();

  const int ll = t & 63;
  const int dgroup = t >> 6;
  float4 p0 = *(const float4*)&s_proj[ll][0];
  float4 p1 = *(const float4*)&s_proj[ll][4];
  for (int j = 0; j < 64; ++j) {
    int dout = dgroup * 64 + j;
    float4 w0 = *(const float4*)&s_dtw[dout * 8];
    float4 w1 = *(const float4*)&s_dtw[dout * 8 + 4];
    float v = s_dtb[dout]
            + p0.x * w0.x + p0.y * w0.y + p0.z * w0.z + p0.w * w0.w
            + p1.x * w1.x + p1.y * w1.y + p1.z * w1.z + p1.w * w1.w;
    dt_t[((size_t)(b * DINNER + dout)) * LSEQ + l0 + ll] = softplus_f(v);
  }
  // Bt/Ct: [B,16,L] — 64 consecutive l-addresses per instruction (coalesced)
  if (t < 64) {
#pragma unroll
    for (int nn = 0; nn < 16; ++nn)
      Bt[((size_t)(b * NSTATE + nn)) * LSEQ + l0 + t] = s_proj[t][8 + nn];
  } else if (t < 128) {
    int lw = t - 64;
#pragma unroll
    for (int nn = 0; nn < 16; ++nn)
      Ct[((size_t)(b * NSTATE + nn)) * LSEQ + l0 + lw] = s_proj[lw][24 + nn];
  }
}

// ---------------------------------------------------------------------------
// Selective scan — EXACT sequential recurrence (same op order / same binary
// reduction tree as the R0/R3 kernels, absmax 1.455e-11). Register-only.
// Per 8-step group: phase 1 = tight h-chain, p[i]=h*C stashed in registers
// (no cross-lane ops on the critical path); phase 2 = 8 independent 4-level
// shfl_xor butterflies, level-interleaved so shuffle latency pipelines.
// 16 lanes (one per state n) per (b,d) channel; 4 channels/wave.
// grid: BATCH * DINNER/4 = 512 blocks of 64 threads.
// ---------------------------------------------------------------------------
__global__ __launch_bounds__(64) void scan_k(
    const float* __restrict__ dt_t, const float* __restrict__ u_t,
    const float* __restrict__ Bt,   const float* __restrict__ Ct,
    const float* __restrict__ A_log, const float* __restrict__ Dp,
    float* __restrict__ y_t)
{
  const int blk = blockIdx.x;
  const int b   = blk >> 6;
  const int d0  = (blk & 63) * 4;
  const int lane = threadIdx.x;
  const int g = lane >> 4;
  const int n = lane & 15;
  const int d = d0 + g;

  const float Aa = -expf(A_log[d * NSTATE + n]);
  const float Dv = Dp[d];
  const float4* dtp = (const float4*)(dt_t + ((size_t)(b * DINNER + d)) * LSEQ);
  const float4* up  = (const float4*)(u_t  + ((size_t)(b * DINNER + d)) * LSEQ);
  const float4* Bp  = (const float4*)(Bt + ((size_t)(b * NSTATE + n)) * LSEQ);
  const float4* Cp  = (const float4*)(Ct + ((size_t)(b * NSTATE + n)) * LSEQ);
  float4* yp = (float4*)(y_t + ((size_t)(b * DINNER + d)) * LSEQ);

  const int NG = LSEQ / 8;             // 512 groups of 8 steps
  float4 Rd[2][2], Ru[2][2], Rb[2][2], Rc[2][2];
  float h = 0.f;

#define LOAD_GRP(s, grp) do {                                            \
    int _base = (grp) * 2;                                               \
    _Pragma("unroll")                                                    \
    for (int q = 0; q < 2; ++q) {                                        \
      Rd[s][q] = dtp[_base + q];  Ru[s][q] = up[_base + q];              \
      Rb[s][q] = Bp[_base + q];   Rc[s][q] = Cp[_base + q];              \
    }                                                                    \
  } while (0)

#define COMP_GRP(s, grp) do {                                            \
    float p[8], us8[8];                                                  \
    _Pragma("unroll")                                                    \
    for (int q = 0; q < 2; ++q) {                                        \
      float dts[4] = {Rd[s][q].x, Rd[s][q].y, Rd[s][q].z, Rd[s][q].w};   \
      float uq[4]  = {Ru[s][q].x, Ru[s][q].y, Ru[s][q].z, Ru[s][q].w};   \
      float bv[4]  = {Rb[s][q].x, Rb[s][q].y, Rb[s][q].z, Rb[s][q].w};   \
      float cv[4]  = {Rc[s][q].x, Rc[s][q].y, Rc[s][q].z, Rc[s][q].w};   \
      _Pragma("unroll")                                                  \
      for (int st = 0; st < 4; ++st) {                                   \
        int i = q * 4 + st;                                              \
        float a = expf(dts[st] * Aa);                                    \
        h = fmaf(a, h, (dts[st] * uq[st]) * bv[st]);                     \
        p[i] = h * cv[st];                                               \
        us8[i] = uq[st];                                                 \
      }                                                                  \
    }                                                                    \
    /* 8 independent butterflies, level-interleaved (same tree as R0) */ \
    _Pragma("unroll")                                                    \
    for (int i = 0; i < 8; ++i) p[i] += __shfl_xor(p[i], 1);             \
    _Pragma("unroll")                                                    \
    for (int i = 0; i < 8; ++i) p[i] += __shfl_xor(p[i], 2);             \
    _Pragma("unroll")                                                    \
    for (int i = 0; i < 8; ++i) p[i] += __shfl_xor(p[i], 4);             \
    _Pragma("unroll")                                                    \
    for (int i = 0; i < 8; ++i) p[i] += __shfl_xor(p[i], 8);             \
    if (n == 0) {                                                        \
      _Pragma("unroll")                                                  \
      for (int q = 0; q < 2; ++q)                                        \
        yp[(grp) * 2 + q] = make_float4(                                 \
            fmaf(us8[q*4+0], Dv, p[q*4+0]),                              \
            fmaf(us8[q*4+1], Dv, p[q*4+1]),                              \
            fmaf(us8[q*4+2], Dv, p[q*4+2]),                              \
            fmaf(us8[q*4+3], Dv, p[q*4+3]));                             \
    }                                                                    \
  } while (0)

  LOAD_GRP(0, 0);
  for (int it = 0; it < NG; it += 2) {
    LOAD_GRP(1, it + 1);
    COMP_GRP(0, it);
    int nx2 = (it + 2 < NG) ? it + 2 : NG - 1;
    LOAD_GRP(0, nx2);
    COMP_GRP(1, it + 1);
  }
#undef LOAD_GRP
#undef COMP_GRP
}

// ---------------------------------------------------------------------------
// ymul[m,d] = y_t[b,d,l] * zs[m,d]   ([B,256,L] -> [M,256] transpose, fused mul)
// ---------------------------------------------------------------------------
__global__ __launch_bounds__(256) void transmul(
    const float* __restrict__ y_t, const float* __restrict__ zs,
    float* __restrict__ outA)
{
  __shared__ float tile[64][129];
  const int b  = blockIdx.z;
  const int d0 = blockIdx.y * 64;
  const int l0 = blockIdx.x * 128;
  const int t  = threadIdx.x;
  const int lc_st = t & 127;
  for (int dd = t >> 7; dd < 64; dd += 2)
    tile[dd][lc_st] = y_t[((size_t)(b * DINNER + d0 + dd)) * LSEQ + l0 + lc_st];
  __syncthreads();
  for (int idx = t; idx < 64 * 128; idx += 256) {
    int dd = idx & 63, lc = idx >> 6;
    size_t addr = ((size_t)(b * LSEQ) + l0 + lc) * DINNER + d0 + dd;
    outA[addr] = tile[dd][lc] * zs[addr];
  }
}

// ---------------------------------------------------------------------------
extern "C" void kernel_launch(void* const* d_in, const int* in_sizes, int n_in,
                              void* d_out, int out_size, void* d_ws, size_t ws_size,
                              hipStream_t stream) {
  const float* x_in  = (const float*)d_in[0];
  const float* w_in  = (const float*)d_in[1];   // [4,512,128]
  const float* cw    = (const float*)d_in[2];   // [4,256,4]
  const float* cb    = (const float*)d_in[3];   // [4,256]
  const float* xpw   = (const float*)d_in[4];   // [4,40,256]
  const float* dtw   = (const float*)d_in[5];   // [4,256,8]
  const float* dtb   = (const float*)d_in[6];   // [4,256]
  const float* alog  = (const float*)d_in[7];   // [4,256,16]
  const float* Dp    = (const float*)d_in[8];   // [4,256]
  const float* ow    = (const float*)d_in[9];   // [4,128,256]
  float* out = (float*)d_out;

  const size_t M = MROWS;
  float* f0 = (float*)d_ws;            // x ping  [M,128]
  float* f1 = f0 + M * 128;            // x pong  [M,128]
  float* f2 = f1 + M * 128;            // xa_pre -> dt_t [B,256,L]
  float* f3 = f2 + M * 256;            // zs = silu(z) [M,256]
  float* f4 = f3 + M * 256;            // xa_t [B,256,L] -> later ymul [M,256]
  float* f6 = f4 + M * 256;            // Bt [B,16,L]
  float* f7 = f6 + M * 16;             // Ct [B,16,L]
  float* f8 = f7 + M * 16;             // y_t [B,256,L]

  const float* cur = x_in;
  for (int i = 0; i < NLAYER; ++i) {
    float* xout = (i == NLAYER - 1) ? out : ((i % 2 == 0) ? f0 : f1);
    const float* wi  = w_in + (size_t)i * 512 * 128;
    const float* cwi = cw   + (size_t)i * 256 * 4;
    const float* cbi = cb   + (size_t)i * 256;
    const float* xpi = xpw  + (size_t)i * 40 * 256;
    const float* dwi = dtw  + (size_t)i * 256 * 8;
    const float* dbi = dtb  + (size_t)i * 256;
    const float* ali = alog + (size_t)i * 256 * 16;
    const float* dpi = Dp   + (size_t)i * 256;
    const float* owi = ow   + (size_t)i * 128 * 256;

    // 1. in_proj: [M,128]@[512,128]^T -> xa_pre(f2), silu(z)(f3)
    gemm_awt<<<dim3(MROWS / 64, 8), 256, 0, stream>>>(
        cur, wi, f2, f3, MROWS, 512, 128, 1);
    // 2. conv + silu + transpose -> xa_t (f4)
    conv_silu_t<<<dim3(LSEQ / 128, DINNER / 64, BATCH), 256, 0, stream>>>(
        f2, cwi, cbi, f4);
    // 3. x_proj + dt_proj + softplus -> dt_t(f2), Bt(f6), Ct(f7)
    proj_dt<<<dim3(LSEQ / 64, BATCH), 256, 0, stream>>>(
        f4, xpi, dwi, dbi, f2, f6, f7);
    // 4. selective scan (exact sequential, deferred butterflies) -> y_t (f8)
    scan_k<<<dim3(BATCH * DINNER / 4), 64, 0, stream>>>(
        f2, f4, f6, f7, ali, dpi, f8);
    // 5. y * silu(z), transpose back -> ymul (f4)
    transmul<<<dim3(LSEQ / 128, DINNER / 64, BATCH), 256, 0, stream>>>(
        f8, f3, f4);
    // 6. out_proj: [M,256]@[128,256]^T -> xout
    gemm_awt<<<dim3(MROWS / 64, 2), 256, 0, stream>>>(
        f4, owi, xout, nullptr, MROWS, 128, 256, 0);

    cur = xout;
  }
}

// Round 6
// 2160.319 us; speedup vs baseline: 1.6449x; 1.0668x over previous
//
#include <hip/hip_runtime.h>
#include <cstddef>

#define BATCH   8
#define LSEQ    4096
#define DMODEL  128
#define DINNER  256
#define NSTATE  16
#define NLAYER  4
#define MROWS   (BATCH*LSEQ)   // 32768

__device__ __forceinline__ float silu_f(float v) { return v / (1.f + expf(-v)); }
__device__ __forceinline__ float softplus_f(float v) {
  return v > 20.f ? v : log1pf(expf(v));
}

// ---------------------------------------------------------------------------
// Generic tiled GEMM: C = A[M,K] @ W[N,K]^T
// mode 0: out0[m*N + n] = c
// mode 1: (N==512) n<256 -> out0[m*256+n] = c (raw xa); n>=256 -> out1 = silu(c)
// ---------------------------------------------------------------------------
__global__ __launch_bounds__(256) void gemm_awt(
    const float* __restrict__ A, const float* __restrict__ W,
    float* __restrict__ out0, float* __restrict__ out1,
    int M, int N, int K, int mode)
{
  __shared__ float As[32][68];
  __shared__ float Bs[32][68];
  const int m0 = blockIdx.x * 64;
  const int n0 = blockIdx.y * 64;
  const int t  = threadIdx.x;
  const int tx = t & 15, ty = t >> 4;
  const int kk_s = t & 31, row_s = t >> 5;

  float acc[4][4] = {};

  for (int k0 = 0; k0 < K; k0 += 32) {
#pragma unroll
    for (int p = 0; p < 8; ++p) {
      int r = row_s + p * 8;
      As[kk_s][r] = A[(size_t)(m0 + r) * K + (k0 + kk_s)];
      Bs[kk_s][r] = W[(size_t)(n0 + r) * K + (k0 + kk_s)];
    }
    __syncthreads();
#pragma unroll
    for (int kk = 0; kk < 32; ++kk) {
      float4 a4 = *(const float4*)&As[kk][ty * 4];
      float4 b4 = *(const float4*)&Bs[kk][tx * 4];
      float av[4] = {a4.x, a4.y, a4.z, a4.w};
      float bv[4] = {b4.x, b4.y, b4.z, b4.w};
#pragma unroll
      for (int i = 0; i < 4; ++i)
#pragma unroll
        for (int j = 0; j < 4; ++j)
          acc[i][j] = fmaf(av[i], bv[j], acc[i][j]);
    }
    __syncthreads();
  }

#pragma unroll
  for (int i = 0; i < 4; ++i) {
    int m = m0 + ty * 4 + i;
    float4 c4 = make_float4(acc[i][0], acc[i][1], acc[i][2], acc[i][3]);
    if (mode == 0) {
      *(float4*)&out0[(size_t)m * N + n0 + tx * 4] = c4;
    } else {
      int n = n0 + tx * 4;
      if (n < 256) {
        *(float4*)&out0[(size_t)m * 256 + n] = c4;
      } else {
        c4.x = silu_f(c4.x); c4.y = silu_f(c4.y);
        c4.z = silu_f(c4.z); c4.w = silu_f(c4.w);
        *(float4*)&out1[(size_t)m * 256 + (n - 256)] = c4;
      }
    }
  }
}

// ---------------------------------------------------------------------------
// Causal depthwise conv (k=4) + bias + silu, with [M,256] -> [B,256,L] transpose
// ---------------------------------------------------------------------------
__global__ __launch_bounds__(256) void conv_silu_t(
    const float* __restrict__ xa_rm,   // [M,256]
    const float* __restrict__ cw,      // [256,4]
    const float* __restrict__ cb,      // [256]
    float* __restrict__ xa_t)          // [B,256,L]
{
  __shared__ float tile[64][133];      // [dd][li], li=0 ~ l0-3
  __shared__ float s_cw[64][4];
  __shared__ float s_cb[64];
  const int b  = blockIdx.z;
  const int d0 = blockIdx.y * 64;
  const int l0 = blockIdx.x * 128;
  const int t  = threadIdx.x;

  if (t < 64) {
    s_cb[t] = cb[d0 + t];
#pragma unroll
    for (int k = 0; k < 4; ++k) s_cw[t][k] = cw[(d0 + t) * 4 + k];
  }
  const int dd_st = t & 63;
  for (int li = t >> 6; li < 131; li += 4) {
    int l = l0 - 3 + li;
    float v = 0.f;
    if (l >= 0) v = xa_rm[((size_t)(b * LSEQ + l)) * 256 + d0 + dd_st];
    tile[dd_st][li] = v;
  }
  __syncthreads();

  for (int idx = t; idx < 64 * 128; idx += 256) {
    int dd = idx >> 7;
    int lc = idx & 127;
    float v = s_cb[dd]
            + tile[dd][lc + 0] * s_cw[dd][0]
            + tile[dd][lc + 1] * s_cw[dd][1]
            + tile[dd][lc + 2] * s_cw[dd][2]
            + tile[dd][lc + 3] * s_cw[dd][3];
    v = silu_f(v);
    xa_t[((size_t)(b * DINNER + d0 + dd)) * LSEQ + l0 + lc] = v;
  }
}

// ---------------------------------------------------------------------------
// Fused x_proj (40x256) + dt_proj (256x8) + softplus.
// Writes dt_t [B,256,L], Bt/Ct [B,16,L]  (state-major, L-contiguous).
// ---------------------------------------------------------------------------
__global__ __launch_bounds__(256) void proj_dt(
    const float* __restrict__ xa_t,    // [B,256,L]
    const float* __restrict__ xp_w,    // [40,256]
    const float* __restrict__ dtp_w,   // [256,8]
    const float* __restrict__ dtp_b,   // [256]
    float* __restrict__ dt_t,          // [B,256,L]
    float* __restrict__ Bt,            // [B,16,L]
    float* __restrict__ Ct)            // [B,16,L]
{
  __shared__ float s_xpc[40][68];
  __shared__ float s_dtw[256 * 8];
  __shared__ float s_dtb[256];
  __shared__ float s_xa[64][68];
  __shared__ float s_proj[64][44];
  const int b  = blockIdx.y;
  const int l0 = blockIdx.x * 64;
  const int t  = threadIdx.x;

  for (int i = t; i < 256 * 8; i += 256) s_dtw[i] = dtp_w[i];
  s_dtb[t] = dtp_b[t];

  const int ll_st  = t & 63;
  const int kk0_st = t >> 6;
  const int kk_w   = t & 63;
  const int nb_w   = t >> 6;
  const int lA = t & 31;
  const int g  = t >> 5;

  float acc0[5] = {}, acc1[5] = {};

  for (int kc = 0; kc < 256; kc += 64) {
    __syncthreads();
#pragma unroll
    for (int p = 0; p < 16; ++p) {
      int kk = kk0_st + p * 4;
      s_xa[ll_st][kk] =
          xa_t[((size_t)(b * DINNER + kc + kk)) * LSEQ + l0 + ll_st];
    }
#pragma unroll
    for (int p = 0; p < 10; ++p) {
      int n = nb_w + p * 4;
      s_xpc[n][kk_w] = xp_w[n * 256 + kc + kk_w];
    }
    __syncthreads();
#pragma unroll
    for (int kk = 0; kk < 64; kk += 4) {
      float4 a0 = *(const float4*)&s_xa[lA][kk];
      float4 a1 = *(const float4*)&s_xa[lA + 32][kk];
#pragma unroll
      for (int j = 0; j < 5; ++j) {
        float4 w4 = *(const float4*)&s_xpc[g * 5 + j][kk];
        acc0[j] = fmaf(a0.x, w4.x, fmaf(a0.y, w4.y,
                  fmaf(a0.z, w4.z, fmaf(a0.w, w4.w, acc0[j]))));
        acc1[j] = fmaf(a1.x, w4.x, fmaf(a1.y, w4.y,
                  fmaf(a1.z, w4.z, fmaf(a1.w, w4.w, acc1[j]))));
      }
    }
  }
  __syncthreads();
#pragma unroll
  for (int j = 0; j < 5; ++j) {
    s_proj[lA][g * 5 + j]      = acc0[j];
    s_proj[lA + 32][g * 5 + j] = acc1[j];
  }
  __syncthreads();

  const int ll = t & 63;
  const int dgroup = t >> 6;
  float4 p0 = *(const float4*)&s_proj[ll][0];
  float4 p1 = *(const float4*)&s_proj[ll][4];
  for (int j = 0; j < 64; ++j) {
    int dout = dgroup * 64 + j;
    float4 w0 = *(const float4*)&s_dtw[dout * 8];
    float4 w1 = *(const float4*)&s_dtw[dout * 8 + 4];
    float v = s_dtb[dout]
            + p0.x * w0.x + p0.y * w0.y + p0.z * w0.z + p0.w * w0.w
            + p1.x * w1.x + p1.y * w1.y + p1.z * w1.z + p1.w * w1.w;
    dt_t[((size_t)(b * DINNER + dout)) * LSEQ + l0 + ll] = softplus_f(v);
  }
  // Bt/Ct: [B,16,L] — 64 consecutive l-addresses per instruction (coalesced)
  if (t < 64) {
#pragma unroll
    for (int nn = 0; nn < 16; ++nn)
      Bt[((size_t)(b * NSTATE + nn)) * LSEQ + l0 + t] = s_proj[t][8 + nn];
  } else if (t < 128) {
    int lw = t - 64;
#pragma unroll
    for (int nn = 0; nn < 16; ++nn)
      Ct[((size_t)(b * NSTATE + nn)) * LSEQ + l0 + lw] = s_proj[lw][24 + nn];
  }
}

// ---------------------------------------------------------------------------
// Selective scan — EXACT sequential recurrence (same op order / same binary
// reduction tree as R0/R3/R5, absmax 1.455e-11). Register-only.
// R5 stalled ~1400 cyc/group on L3/HBM load latency with prefetch depth 1;
// this version keeps a 4-deep register ring (32 timesteps in flight) so
// steady-state time/group ~= max(compute, latency/4).
// 16 lanes (one per state n) per (b,d) channel; 4 channels/wave.
// grid: BATCH * DINNER/4 = 512 blocks of 64 threads (2 waves/CU — fixed by
// the exact-sequential constraint; all latency hiding is intra-wave ILP).
// ---------------------------------------------------------------------------
__global__ __launch_bounds__(64) void scan_k(
    const float* __restrict__ dt_t, const float* __restrict__ u_t,
    const float* __restrict__ Bt,   const float* __restrict__ Ct,
    const float* __restrict__ A_log, const float* __restrict__ Dp,
    float* __restrict__ y_t)
{
  const int blk = blockIdx.x;
  const int b   = blk >> 6;
  const int d0  = (blk & 63) * 4;
  const int lane = threadIdx.x;
  const int g = lane >> 4;
  const int n = lane & 15;
  const int d = d0 + g;

  const float Aa = -expf(A_log[d * NSTATE + n]);
  const float Dv = Dp[d];
  const float4* dtp = (const float4*)(dt_t + ((size_t)(b * DINNER + d)) * LSEQ);
  const float4* up  = (const float4*)(u_t  + ((size_t)(b * DINNER + d)) * LSEQ);
  const float4* Bp  = (const float4*)(Bt + ((size_t)(b * NSTATE + n)) * LSEQ);
  const float4* Cp  = (const float4*)(Ct + ((size_t)(b * NSTATE + n)) * LSEQ);
  float4* yp = (float4*)(y_t + ((size_t)(b * DINNER + d)) * LSEQ);

  const int NG = LSEQ / 8;             // 512 groups of 8 steps
  float4 Rd[4][2], Ru[4][2], Rb[4][2], Rc[4][2];   // 4-deep ring
  float h = 0.f;

#define LOAD_GRP(s, grp) do {                                            \
    int _gg = (grp) < NG ? (grp) : NG - 1;                               \
    int _base = _gg * 2;                                                 \
    _Pragma("unroll")                                                    \
    for (int q = 0; q < 2; ++q) {                                        \
      Rd[s][q] = dtp[_base + q];  Ru[s][q] = up[_base + q];              \
      Rb[s][q] = Bp[_base + q];   Rc[s][q] = Cp[_base + q];              \
    }                                                                    \
  } while (0)

#define COMP_GRP(s, grp) do {                                            \
    float p[8], us8[8];                                                  \
    _Pragma("unroll")                                                    \
    for (int q = 0; q < 2; ++q) {                                        \
      float dts[4] = {Rd[s][q].x, Rd[s][q].y, Rd[s][q].z, Rd[s][q].w};   \
      float uq[4]  = {Ru[s][q].x, Ru[s][q].y, Ru[s][q].z, Ru[s][q].w};   \
      float bv[4]  = {Rb[s][q].x, Rb[s][q].y, Rb[s][q].z, Rb[s][q].w};   \
      float cv[4]  = {Rc[s][q].x, Rc[s][q].y, Rc[s][q].z, Rc[s][q].w};   \
      _Pragma("unroll")                                                  \
      for (int st = 0; st < 4; ++st) {                                   \
        int i = q * 4 + st;                                              \
        float a = expf(dts[st] * Aa);                                    \
        h = fmaf(a, h, (dts[st] * uq[st]) * bv[st]);                     \
        p[i] = h * cv[st];                                               \
        us8[i] = uq[st];                                                 \
      }                                                                  \
    }                                                                    \
    /* 8 independent butterflies, level-interleaved (same tree as R0) */ \
    _Pragma("unroll")                                                    \
    for (int i = 0; i < 8; ++i) p[i] += __shfl_xor(p[i], 1);             \
    _Pragma("unroll")                                                    \
    for (int i = 0; i < 8; ++i) p[i] += __shfl_xor(p[i], 2);             \
    _Pragma("unroll")                                                    \
    for (int i = 0; i < 8; ++i) p[i] += __shfl_xor(p[i], 4);             \
    _Pragma("unroll")                                                    \
    for (int i = 0; i < 8; ++i) p[i] += __shfl_xor(p[i], 8);             \
    if (n == 0) {                                                        \
      _Pragma("unroll")                                                  \
      for (int q = 0; q < 2; ++q)                                        \
        yp[(grp) * 2 + q] = make_float4(                                 \
            fmaf(us8[q*4+0], Dv, p[q*4+0]),                              \
            fmaf(us8[q*4+1], Dv, p[q*4+1]),                              \
            fmaf(us8[q*4+2], Dv, p[q*4+2]),                              \
            fmaf(us8[q*4+3], Dv, p[q*4+3]));                             \
    }                                                                    \
  } while (0)

  LOAD_GRP(0, 0);
  LOAD_GRP(1, 1);
  LOAD_GRP(2, 2);
  for (int it = 0; it < NG; it += 4) {
    LOAD_GRP(3, it + 3);
    COMP_GRP(0, it);
    LOAD_GRP(0, it + 4);
    COMP_GRP(1, it + 1);
    LOAD_GRP(1, it + 5);
    COMP_GRP(2, it + 2);
    LOAD_GRP(2, it + 6);
    COMP_GRP(3, it + 3);
  }
#undef LOAD_GRP
#undef COMP_GRP
}

// ---------------------------------------------------------------------------
// ymul[m,d] = y_t[b,d,l] * zs[m,d]   ([B,256,L] -> [M,256] transpose, fused mul)
// ---------------------------------------------------------------------------
__global__ __launch_bounds__(256) void transmul(
    const float* __restrict__ y_t, const float* __restrict__ zs,
    float* __restrict__ outA)
{
  __shared__ float tile[64][129];
  const int b  = blockIdx.z;
  const int d0 = blockIdx.y * 64;
  const int l0 = blockIdx.x * 128;
  const int t  = threadIdx.x;
  const int lc_st = t & 127;
  for (int dd = t >> 7; dd < 64; dd += 2)
    tile[dd][lc_st] = y_t[((size_t)(b * DINNER + d0 + dd)) * LSEQ + l0 + lc_st];
  __syncthreads();
  for (int idx = t; idx < 64 * 128; idx += 256) {
    int dd = idx & 63, lc = idx >> 6;
    size_t addr = ((size_t)(b * LSEQ) + l0 + lc) * DINNER + d0 + dd;
    outA[addr] = tile[dd][lc] * zs[addr];
  }
}

// ---------------------------------------------------------------------------
extern "C" void kernel_launch(void* const* d_in, const int* in_sizes, int n_in,
                              void* d_out, int out_size, void* d_ws, size_t ws_size,
                              hipStream_t stream) {
  const float* x_in  = (const float*)d_in[0];
  const float* w_in  = (const float*)d_in[1];   // [4,512,128]
  const float* cw    = (const float*)d_in[2];   // [4,256,4]
  const float* cb    = (const float*)d_in[3];   // [4,256]
  const float* xpw   = (const float*)d_in[4];   // [4,40,256]
  const float* dtw   = (const float*)d_in[5];   // [4,256,8]
  const float* dtb   = (const float*)d_in[6];   // [4,256]
  const float* alog  = (const float*)d_in[7];   // [4,256,16]
  const float* Dp    = (const float*)d_in[8];   // [4,256]
  const float* ow    = (const float*)d_in[9];   // [4,128,256]
  float* out = (float*)d_out;

  const size_t M = MROWS;
  float* f0 = (float*)d_ws;            // x ping  [M,128]
  float* f1 = f0 + M * 128;            // x pong  [M,128]
  float* f2 = f1 + M * 128;            // xa_pre -> dt_t [B,256,L]
  float* f3 = f2 + M * 256;            // zs = silu(z) [M,256]
  float* f4 = f3 + M * 256;            // xa_t [B,256,L] -> later ymul [M,256]
  float* f6 = f4 + M * 256;            // Bt [B,16,L]
  float* f7 = f6 + M * 16;             // Ct [B,16,L]
  float* f8 = f7 + M * 16;             // y_t [B,256,L]

  const float* cur = x_in;
  for (int i = 0; i < NLAYER; ++i) {
    float* xout = (i == NLAYER - 1) ? out : ((i % 2 == 0) ? f0 : f1);
    const float* wi  = w_in + (size_t)i * 512 * 128;
    const float* cwi = cw   + (size_t)i * 256 * 4;
    const float* cbi = cb   + (size_t)i * 256;
    const float* xpi = xpw  + (size_t)i * 40 * 256;
    const float* dwi = dtw  + (size_t)i * 256 * 8;
    const float* dbi = dtb  + (size_t)i * 256;
    const float* ali = alog + (size_t)i * 256 * 16;
    const float* dpi = Dp   + (size_t)i * 256;
    const float* owi = ow   + (size_t)i * 128 * 256;

    // 1. in_proj: [M,128]@[512,128]^T -> xa_pre(f2), silu(z)(f3)
    gemm_awt<<<dim3(MROWS / 64, 8), 256, 0, stream>>>(
        cur, wi, f2, f3, MROWS, 512, 128, 1);
    // 2. conv + silu + transpose -> xa_t (f4)
    conv_silu_t<<<dim3(LSEQ / 128, DINNER / 64, BATCH), 256, 0, stream>>>(
        f2, cwi, cbi, f4);
    // 3. x_proj + dt_proj + softplus -> dt_t(f2), Bt(f6), Ct(f7)
    proj_dt<<<dim3(LSEQ / 64, BATCH), 256, 0, stream>>>(
        f4, xpi, dwi, dbi, f2, f6, f7);
    // 4. selective scan (exact sequential, 4-deep prefetch ring) -> y_t (f8)
    scan_k<<<dim3(BATCH * DINNER / 4), 64, 0, stream>>>(
        f2, f4, f6, f7, ali, dpi, f8);
    // 5. y * silu(z), transpose back -> ymul (f4)
    transmul<<<dim3(LSEQ / 128, DINNER / 64, BATCH), 256, 0, stream>>>(
        f8, f3, f4);
    // 6. out_proj: [M,256]@[128,256]^T -> xout
    gemm_awt<<<dim3(MROWS / 64, 2), 256, 0, stream>>>(
        f4, owi, xout, nullptr, MROWS, 128, 256, 0);

    cur = xout;
  }
}

// Round 7
// 2127.296 us; speedup vs baseline: 1.6704x; 1.0155x over previous
//
#include <hip/hip_runtime.h>
#include <cstddef>

#define BATCH   8
#define LSEQ    4096
#define DMODEL  128
#define DINNER  256
#define NSTATE  16
#define NLAYER  4
#define MROWS   (BATCH*LSEQ)   // 32768

__device__ __forceinline__ float silu_f(float v) { return v / (1.f + expf(-v)); }
__device__ __forceinline__ float softplus_f(float v) {
  return v > 20.f ? v : log1pf(expf(v));
}

// ---------------------------------------------------------------------------
// Generic tiled GEMM: C = A[M,K] @ W[N,K]^T
// mode 0: out0[m*N + n] = c
// mode 1: (N==512) n<256 -> out0[m*256+n] = c (raw xa); n>=256 -> out1 = silu(c)
// ---------------------------------------------------------------------------
__global__ __launch_bounds__(256) void gemm_awt(
    const float* __restrict__ A, const float* __restrict__ W,
    float* __restrict__ out0, float* __restrict__ out1,
    int M, int N, int K, int mode)
{
  __shared__ float As[32][68];
  __shared__ float Bs[32][68];
  const int m0 = blockIdx.x * 64;
  const int n0 = blockIdx.y * 64;
  const int t  = threadIdx.x;
  const int tx = t & 15, ty = t >> 4;
  const int kk_s = t & 31, row_s = t >> 5;

  float acc[4][4] = {};

  for (int k0 = 0; k0 < K; k0 += 32) {
#pragma unroll
    for (int p = 0; p < 8; ++p) {
      int r = row_s + p * 8;
      As[kk_s][r] = A[(size_t)(m0 + r) * K + (k0 + kk_s)];
      Bs[kk_s][r] = W[(size_t)(n0 + r) * K + (k0 + kk_s)];
    }
    __syncthreads();
#pragma unroll
    for (int kk = 0; kk < 32; ++kk) {
      float4 a4 = *(const float4*)&As[kk][ty * 4];
      float4 b4 = *(const float4*)&Bs[kk][tx * 4];
      float av[4] = {a4.x, a4.y, a4.z, a4.w};
      float bv[4] = {b4.x, b4.y, b4.z, b4.w};
#pragma unroll
      for (int i = 0; i < 4; ++i)
#pragma unroll
        for (int j = 0; j < 4; ++j)
          acc[i][j] = fmaf(av[i], bv[j], acc[i][j]);
    }
    __syncthreads();
  }

#pragma unroll
  for (int i = 0; i < 4; ++i) {
    int m = m0 + ty * 4 + i;
    float4 c4 = make_float4(acc[i][0], acc[i][1], acc[i][2], acc[i][3]);
    if (mode == 0) {
      *(float4*)&out0[(size_t)m * N + n0 + tx * 4] = c4;
    } else {
      int n = n0 + tx * 4;
      if (n < 256) {
        *(float4*)&out0[(size_t)m * 256 + n] = c4;
      } else {
        c4.x = silu_f(c4.x); c4.y = silu_f(c4.y);
        c4.z = silu_f(c4.z); c4.w = silu_f(c4.w);
        *(float4*)&out1[(size_t)m * 256 + (n - 256)] = c4;
      }
    }
  }
}

// ---------------------------------------------------------------------------
// Causal depthwise conv (k=4) + bias + silu, with [M,256] -> [B,256,L] transpose
// ---------------------------------------------------------------------------
__global__ __launch_bounds__(256) void conv_silu_t(
    const float* __restrict__ xa_rm,   // [M,256]
    const float* __restrict__ cw,      // [256,4]
    const float* __restrict__ cb,      // [256]
    float* __restrict__ xa_t)          // [B,256,L]
{
  __shared__ float tile[64][133];      // [dd][li], li=0 ~ l0-3
  __shared__ float s_cw[64][4];
  __shared__ float s_cb[64];
  const int b  = blockIdx.z;
  const int d0 = blockIdx.y * 64;
  const int l0 = blockIdx.x * 128;
  const int t  = threadIdx.x;

  if (t < 64) {
    s_cb[t] = cb[d0 + t];
#pragma unroll
    for (int k = 0; k < 4; ++k) s_cw[t][k] = cw[(d0 + t) * 4 + k];
  }
  const int dd_st = t & 63;
  for (int li = t >> 6; li < 131; li += 4) {
    int l = l0 - 3 + li;
    float v = 0.f;
    if (l >= 0) v = xa_rm[((size_t)(b * LSEQ + l)) * 256 + d0 + dd_st];
    tile[dd_st][li] = v;
  }
  __syncthreads();

  for (int idx = t; idx < 64 * 128; idx += 256) {
    int dd = idx >> 7;
    int lc = idx & 127;
    float v = s_cb[dd]
            + tile[dd][lc + 0] * s_cw[dd][0]
            + tile[dd][lc + 1] * s_cw[dd][1]
            + tile[dd][lc + 2] * s_cw[dd][2]
            + tile[dd][lc + 3] * s_cw[dd][3];
    v = silu_f(v);
    xa_t[((size_t)(b * DINNER + d0 + dd)) * LSEQ + l0 + lc] = v;
  }
}

// ---------------------------------------------------------------------------
// Fused x_proj (40x256) + dt_proj (256x8) + softplus.
// Writes dt_t [B,256,L], Bt/Ct [B,16,L]  (state-major, L-contiguous).
// ---------------------------------------------------------------------------
__global__ __launch_bounds__(256) void proj_dt(
    const float* __restrict__ xa_t,    // [B,256,L]
    const float* __restrict__ xp_w,    // [40,256]
    const float* __restrict__ dtp_w,   // [256,8]
    const float* __restrict__ dtp_b,   // [256]
    float* __restrict__ dt_t,          // [B,256,L]
    float* __restrict__ Bt,            // [B,16,L]
    float* __restrict__ Ct)            // [B,16,L]
{
  __shared__ float s_xpc[40][68];
  __shared__ float s_dtw[256 * 8];
  __shared__ float s_dtb[256];
  __shared__ float s_xa[64][68];
  __shared__ float s_proj[64][44];
  const int b  = blockIdx.y;
  const int l0 = blockIdx.x * 64;
  const int t  = threadIdx.x;

  for (int i = t; i < 256 * 8; i += 256) s_dtw[i] = dtp_w[i];
  s_dtb[t] = dtp_b[t];

  const int ll_st  = t & 63;
  const int kk0_st = t >> 6;
  const int kk_w   = t & 63;
  const int nb_w   = t >> 6;
  const int lA = t & 31;
  const int g  = t >> 5;

  float acc0[5] = {}, acc1[5] = {};

  for (int kc = 0; kc < 256; kc += 64) {
    __syncthreads();
#pragma unroll
    for (int p = 0; p < 16; ++p) {
      int kk = kk0_st + p * 4;
      s_xa[ll_st][kk] =
          xa_t[((size_t)(b * DINNER + kc + kk)) * LSEQ + l0 + ll_st];
    }
#pragma unroll
    for (int p = 0; p < 10; ++p) {
      int n = nb_w + p * 4;
      s_xpc[n][kk_w] = xp_w[n * 256 + kc + kk_w];
    }
    __syncthreads();
#pragma unroll
    for (int kk = 0; kk < 64; kk += 4) {
      float4 a0 = *(const float4*)&s_xa[lA][kk];
      float4 a1 = *(const float4*)&s_xa[lA + 32][kk];
#pragma unroll
      for (int j = 0; j < 5; ++j) {
        float4 w4 = *(const float4*)&s_xpc[g * 5 + j][kk];
        acc0[j] = fmaf(a0.x, w4.x, fmaf(a0.y, w4.y,
                  fmaf(a0.z, w4.z, fmaf(a0.w, w4.w, acc0[j]))));
        acc1[j] = fmaf(a1.x, w4.x, fmaf(a1.y, w4.y,
                  fmaf(a1.z, w4.z, fmaf(a1.w, w4.w, acc1[j]))));
      }
    }
  }
  __syncthreads();
#pragma unroll
  for (int j = 0; j < 5; ++j) {
    s_proj[lA][g * 5 + j]      = acc0[j];
    s_proj[lA + 32][g * 5 + j] = acc1[j];
  }
  __syncthreads();

  const int ll = t & 63;
  const int dgroup = t >> 6;
  float4 p0 = *(const float4*)&s_proj[ll][0];
  float4 p1 = *(const float4*)&s_proj[ll][4];
  for (int j = 0; j < 64; ++j) {
    int dout = dgroup * 64 + j;
    float4 w0 = *(const float4*)&s_dtw[dout * 8];
    float4 w1 = *(const float4*)&s_dtw[dout * 8 + 4];
    float v = s_dtb[dout]
            + p0.x * w0.x + p0.y * w0.y + p0.z * w0.z + p0.w * w0.w
            + p1.x * w1.x + p1.y * w1.y + p1.z * w1.z + p1.w * w1.w;
    dt_t[((size_t)(b * DINNER + dout)) * LSEQ + l0 + ll] = softplus_f(v);
  }
  // Bt/Ct: [B,16,L] — 64 consecutive l-addresses per instruction (coalesced)
  if (t < 64) {
#pragma unroll
    for (int nn = 0; nn < 16; ++nn)
      Bt[((size_t)(b * NSTATE + nn)) * LSEQ + l0 + t] = s_proj[t][8 + nn];
  } else if (t < 128) {
    int lw = t - 64;
#pragma unroll
    for (int nn = 0; nn < 16; ++nn)
      Ct[((size_t)(b * NSTATE + nn)) * LSEQ + l0 + lw] = s_proj[lw][24 + nn];
  }
}

// ---------------------------------------------------------------------------
// Selective scan — EXACT sequential recurrence (same op order / same binary
// reduction tree as R0/R3/R5/R6, absmax 1.455e-11). Register-only 4-deep
// prefetch ring. R6's counters (VGPR=80) proved the pre-RA scheduler sank
// the ring loads back to their uses, collapsing prefetch depth to ~1.5.
// sched_barrier(0) between every LOAD/COMP phase pins the issue order, so
// the backend's waitcnt pass emits fine-grained vmcnt(~24) waits instead of
// draining. At ~1 wave/SIMD occupancy, VGPR pressure up to 256 is free.
// grid: BATCH * DINNER/4 = 512 blocks of 64 threads.
// ---------------------------------------------------------------------------
__global__ __launch_bounds__(64) void scan_k(
    const float* __restrict__ dt_t, const float* __restrict__ u_t,
    const float* __restrict__ Bt,   const float* __restrict__ Ct,
    const float* __restrict__ A_log, const float* __restrict__ Dp,
    float* __restrict__ y_t)
{
  const int blk = blockIdx.x;
  const int b   = blk >> 6;
  const int d0  = (blk & 63) * 4;
  const int lane = threadIdx.x;
  const int g = lane >> 4;
  const int n = lane & 15;
  const int d = d0 + g;

  const float Aa = -expf(A_log[d * NSTATE + n]);
  const float Dv = Dp[d];
  const float4* dtp = (const float4*)(dt_t + ((size_t)(b * DINNER + d)) * LSEQ);
  const float4* up  = (const float4*)(u_t  + ((size_t)(b * DINNER + d)) * LSEQ);
  const float4* Bp  = (const float4*)(Bt + ((size_t)(b * NSTATE + n)) * LSEQ);
  const float4* Cp  = (const float4*)(Ct + ((size_t)(b * NSTATE + n)) * LSEQ);
  float4* yp = (float4*)(y_t + ((size_t)(b * DINNER + d)) * LSEQ);

  const int NG = LSEQ / 8;             // 512 groups of 8 steps
  float4 Rd[4][2], Ru[4][2], Rb[4][2], Rc[4][2];   // 4-deep ring
  float h = 0.f;

#define SCHED_FENCE() __builtin_amdgcn_sched_barrier(0)

#define LOAD_GRP(s, grp) do {                                            \
    int _gg = (grp) < NG ? (grp) : NG - 1;                               \
    int _base = _gg * 2;                                                 \
    _Pragma("unroll")                                                    \
    for (int q = 0; q < 2; ++q) {                                        \
      Rd[s][q] = dtp[_base + q];  Ru[s][q] = up[_base + q];              \
      Rb[s][q] = Bp[_base + q];   Rc[s][q] = Cp[_base + q];              \
    }                                                                    \
  } while (0)

#define COMP_GRP(s, grp) do {                                            \
    float p[8], us8[8];                                                  \
    _Pragma("unroll")                                                    \
    for (int q = 0; q < 2; ++q) {                                        \
      float dts[4] = {Rd[s][q].x, Rd[s][q].y, Rd[s][q].z, Rd[s][q].w};   \
      float uq[4]  = {Ru[s][q].x, Ru[s][q].y, Ru[s][q].z, Ru[s][q].w};   \
      float bv[4]  = {Rb[s][q].x, Rb[s][q].y, Rb[s][q].z, Rb[s][q].w};   \
      float cv[4]  = {Rc[s][q].x, Rc[s][q].y, Rc[s][q].z, Rc[s][q].w};   \
      _Pragma("unroll")                                                  \
      for (int st = 0; st < 4; ++st) {                                   \
        int i = q * 4 + st;                                              \
        float a = expf(dts[st] * Aa);                                    \
        h = fmaf(a, h, (dts[st] * uq[st]) * bv[st]);                     \
        p[i] = h * cv[st];                                               \
        us8[i] = uq[st];                                                 \
      }                                                                  \
    }                                                                    \
    /* 8 independent butterflies, level-interleaved (same tree as R0) */ \
    _Pragma("unroll")                                                    \
    for (int i = 0; i < 8; ++i) p[i] += __shfl_xor(p[i], 1);             \
    _Pragma("unroll")                                                    \
    for (int i = 0; i < 8; ++i) p[i] += __shfl_xor(p[i], 2);             \
    _Pragma("unroll")                                                    \
    for (int i = 0; i < 8; ++i) p[i] += __shfl_xor(p[i], 4);             \
    _Pragma("unroll")                                                    \
    for (int i = 0; i < 8; ++i) p[i] += __shfl_xor(p[i], 8);             \
    if (n == 0) {                                                        \
      _Pragma("unroll")                                                  \
      for (int q = 0; q < 2; ++q)                                        \
        yp[(grp) * 2 + q] = make_float4(                                 \
            fmaf(us8[q*4+0], Dv, p[q*4+0]),                              \
            fmaf(us8[q*4+1], Dv, p[q*4+1]),                              \
            fmaf(us8[q*4+2], Dv, p[q*4+2]),                              \
            fmaf(us8[q*4+3], Dv, p[q*4+3]));                             \
    }                                                                    \
  } while (0)

  LOAD_GRP(0, 0);
  SCHED_FENCE();
  LOAD_GRP(1, 1);
  SCHED_FENCE();
  LOAD_GRP(2, 2);
  SCHED_FENCE();
  for (int it = 0; it < NG; it += 4) {
    LOAD_GRP(3, it + 3);
    SCHED_FENCE();
    COMP_GRP(0, it);
    SCHED_FENCE();
    LOAD_GRP(0, it + 4);
    SCHED_FENCE();
    COMP_GRP(1, it + 1);
    SCHED_FENCE();
    LOAD_GRP(1, it + 5);
    SCHED_FENCE();
    COMP_GRP(2, it + 2);
    SCHED_FENCE();
    LOAD_GRP(2, it + 6);
    SCHED_FENCE();
    COMP_GRP(3, it + 3);
    SCHED_FENCE();
  }
#undef LOAD_GRP
#undef COMP_GRP
#undef SCHED_FENCE
}

// ---------------------------------------------------------------------------
// ymul[m,d] = y_t[b,d,l] * zs[m,d]   ([B,256,L] -> [M,256] transpose, fused mul)
// ---------------------------------------------------------------------------
__global__ __launch_bounds__(256) void transmul(
    const float* __restrict__ y_t, const float* __restrict__ zs,
    float* __restrict__ outA)
{
  __shared__ float tile[64][129];
  const int b  = blockIdx.z;
  const int d0 = blockIdx.y * 64;
  const int l0 = blockIdx.x * 128;
  const int t  = threadIdx.x;
  const int lc_st = t & 127;
  for (int dd = t >> 7; dd < 64; dd += 2)
    tile[dd][lc_st] = y_t[((size_t)(b * DINNER + d0 + dd)) * LSEQ + l0 + lc_st];
  __syncthreads();
  for (int idx = t; idx < 64 * 128; idx += 256) {
    int dd = idx & 63, lc = idx >> 6;
    size_t addr = ((size_t)(b * LSEQ) + l0 + lc) * DINNER + d0 + dd;
    outA[addr] = tile[dd][lc] * zs[addr];
  }
}

// ---------------------------------------------------------------------------
extern "C" void kernel_launch(void* const* d_in, const int* in_sizes, int n_in,
                              void* d_out, int out_size, void* d_ws, size_t ws_size,
                              hipStream_t stream) {
  const float* x_in  = (const float*)d_in[0];
  const float* w_in  = (const float*)d_in[1];   // [4,512,128]
  const float* cw    = (const float*)d_in[2];   // [4,256,4]
  const float* cb    = (const float*)d_in[3];   // [4,256]
  const float* xpw   = (const float*)d_in[4];   // [4,40,256]
  const float* dtw   = (const float*)d_in[5];   // [4,256,8]
  const float* dtb   = (const float*)d_in[6];   // [4,256]
  const float* alog  = (const float*)d_in[7];   // [4,256,16]
  const float* Dp    = (const float*)d_in[8];   // [4,256]
  const float* ow    = (const float*)d_in[9];   // [4,128,256]
  float* out = (float*)d_out;

  const size_t M = MROWS;
  float* f0 = (float*)d_ws;            // x ping  [M,128]
  float* f1 = f0 + M * 128;            // x pong  [M,128]
  float* f2 = f1 + M * 128;            // xa_pre -> dt_t [B,256,L]
  float* f3 = f2 + M * 256;            // zs = silu(z) [M,256]
  float* f4 = f3 + M * 256;            // xa_t [B,256,L] -> later ymul [M,256]
  float* f6 = f4 + M * 256;            // Bt [B,16,L]
  float* f7 = f6 + M * 16;             // Ct [B,16,L]
  float* f8 = f7 + M * 16;             // y_t [B,256,L]

  const float* cur = x_in;
  for (int i = 0; i < NLAYER; ++i) {
    float* xout = (i == NLAYER - 1) ? out : ((i % 2 == 0) ? f0 : f1);
    const float* wi  = w_in + (size_t)i * 512 * 128;
    const float* cwi = cw   + (size_t)i * 256 * 4;
    const float* cbi = cb   + (size_t)i * 256;
    const float* xpi = xpw  + (size_t)i * 40 * 256;
    const float* dwi = dtw  + (size_t)i * 256 * 8;
    const float* dbi = dtb  + (size_t)i * 256;
    const float* ali = alog + (size_t)i * 256 * 16;
    const float* dpi = Dp   + (size_t)i * 256;
    const float* owi = ow   + (size_t)i * 128 * 256;

    // 1. in_proj: [M,128]@[512,128]^T -> xa_pre(f2), silu(z)(f3)
    gemm_awt<<<dim3(MROWS / 64, 8), 256, 0, stream>>>(
        cur, wi, f2, f3, MROWS, 512, 128, 1);
    // 2. conv + silu + transpose -> xa_t (f4)
    conv_silu_t<<<dim3(LSEQ / 128, DINNER / 64, BATCH), 256, 0, stream>>>(
        f2, cwi, cbi, f4);
    // 3. x_proj + dt_proj + softplus -> dt_t(f2), Bt(f6), Ct(f7)
    proj_dt<<<dim3(LSEQ / 64, BATCH), 256, 0, stream>>>(
        f4, xpi, dwi, dbi, f2, f6, f7);
    // 4. selective scan (exact sequential, pinned 4-deep prefetch) -> y_t (f8)
    scan_k<<<dim3(BATCH * DINNER / 4), 64, 0, stream>>>(
        f2, f4, f6, f7, ali, dpi, f8);
    // 5. y * silu(z), transpose back -> ymul (f4)
    transmul<<<dim3(LSEQ / 128, DINNER / 64, BATCH), 256, 0, stream>>>(
        f8, f3, f4);
    // 6. out_proj: [M,256]@[128,256]^T -> xout
    gemm_awt<<<dim3(MROWS / 64, 2), 256, 0, stream>>>(
        f4, owi, xout, nullptr, MROWS, 128, 256, 0);

    cur = xout;
  }
}